// Round 3
// baseline (486.442 us; speedup 1.0000x reference)
//
#include <hip/hip_runtime.h>
#include <math.h>

#define LEN_IN_C 20197
#define BATCH_C 2
#define BL_C (BATCH_C * LEN_IN_C)   // 40394

typedef short  bf16x8 __attribute__((ext_vector_type(8)));
typedef float  f32x4  __attribute__((ext_vector_type(4)));

__device__ __forceinline__ ushort f2bf(float f) {
    unsigned u = __float_as_uint(f);
    return (ushort)((u + 0x7fffu + ((u >> 16) & 1u)) >> 16);
}
__device__ __forceinline__ float bf2f(ushort u) {
    return __uint_as_float((uint)u << 16);
}
__device__ __forceinline__ uint pkbf(float a, float b) {
    uint r;
    asm("v_cvt_pk_bf16_f32 %0, %1, %2" : "=v"(r) : "v"(a), "v"(b));
    return r;
}
__device__ __forceinline__ bf16x8 ld_cvt(const float* p) {
    float4 f0 = *(const float4*)p;
    float4 f1 = *(const float4*)(p + 4);
    union { bf16x8 v; uint u[4]; } r;
    r.u[0] = pkbf(f0.x, f0.y); r.u[1] = pkbf(f0.z, f0.w);
    r.u[2] = pkbf(f1.x, f1.y); r.u[3] = pkbf(f1.z, f1.w);
    return r.v;
}

// ---------------- weight transpose + cast: W (K x N f32) -> WT (N x K bf16) ----------
__global__ __launch_bounds__(256) void transpose_cast(
    const float* __restrict__ W, ushort* __restrict__ WT, int K, int N)
{
    __shared__ float tile[32][33];
    const int n0 = blockIdx.x * 32, k0 = blockIdx.y * 32;
    const int ty = threadIdx.x >> 3, tx = threadIdx.x & 7;
    float4 v = *(const float4*)(W + (size_t)(k0 + ty) * N + n0 + tx * 4);
    tile[ty][tx * 4 + 0] = v.x; tile[ty][tx * 4 + 1] = v.y;
    tile[ty][tx * 4 + 2] = v.z; tile[ty][tx * 4 + 3] = v.w;
    __syncthreads();
    ushort4 o;
    o.x = f2bf(tile[tx * 4 + 0][ty]);
    o.y = f2bf(tile[tx * 4 + 1][ty]);
    o.z = f2bf(tile[tx * 4 + 2][ty]);
    o.w = f2bf(tile[tx * 4 + 3][ty]);
    *(ushort4*)(WT + (size_t)(n0 + ty) * K + k0 + tx * 4) = o;
}

// -------- combined-B builder: BT (640 x 512 bf16) = [[Wv Wo Wa],[0 Wo Wa]]^T --------
__global__ __launch_bounds__(256) void build_comb(
    const float* __restrict__ Wv, const float* __restrict__ Wo,
    const float* __restrict__ Wa, ushort* __restrict__ BT)
{
    const int idx = blockIdx.x * 256 + threadIdx.x;   // 640*128 total
    const int n = idx >> 7, k4 = (idx & 127) * 4;
    ushort4 o;
    ushort* po = (ushort*)&o;
    #pragma unroll
    for (int j = 0; j < 4; ++j) {
        const int k = k4 + j, kk = k & 255;
        float v;
        if (n < 256)      v = (k < 256) ? Wv[(size_t)kk * 256 + n] : 0.f;
        else if (n < 512) v = Wo[(size_t)kk * 256 + (n - 256)];
        else              v = Wa[(size_t)kk * 128 + (n - 512)];
        po[j] = f2bf(v);
    }
    *(ushort4*)(BT + (size_t)n * 512 + k4) = o;
}

__global__ __launch_bounds__(256) void build_bias(
    const float* __restrict__ bv, const float* __restrict__ bo,
    const float* __restrict__ ba, float* __restrict__ out)
{
    const int n = blockIdx.x * 256 + threadIdx.x;
    if (n >= 640) return;
    out[n] = (n < 256) ? bv[n] : (n < 512) ? bo[n - 256] : ba[n - 512];
}

// ---------------- LDS-free direct-register MFMA GEMM ----------------
// C(bf16, M x N) = A @ BT^T + bias.  BM=128, BN=128, 4 waves (2x2), wave 64x64.
// AMODE 0: A bf16 row-major (stride sa). AMODE 3: A=[Af32 | A2f32] along K (each 256).
template <int AMODE, bool RELU>
__global__ __launch_bounds__(256, 2) void gemm_dr(
    const void* __restrict__ Av, const void* __restrict__ A2v,
    const ushort* __restrict__ BT, const float* __restrict__ bias,
    ushort* __restrict__ C, const int M, const int N, const int K,
    const int sa, const int ntiles, const int nwg)
{
    // bijective XCD chunk swizzle; N-fast within chunk -> per-XCD A-slice L2 reuse
    const int lid = blockIdx.x;
    const int q = nwg >> 3, r = nwg & 7;
    const int xcd = lid & 7, p = lid >> 3;
    const int nid = (xcd < r ? xcd * (q + 1) : r * (q + 1) + (xcd - r) * q) + p;
    const int nt = nid % ntiles, mt = nid / ntiles;
    const int row0 = mt * 128, col0 = nt * 128;

    const int ln = threadIdx.x & 63, wv = threadIdx.x >> 6;
    const int wm = wv >> 1, wn = wv & 1;
    const int l16 = ln & 15, lk = ln >> 4;

    const ushort* bp[4];
    #pragma unroll
    for (int n = 0; n < 4; ++n)
        bp[n] = BT + (size_t)(col0 + wn * 64 + n * 16 + l16) * K + lk * 8;

    size_t aoff[4];
    #pragma unroll
    for (int m = 0; m < 4; ++m) {
        int rrow = row0 + wm * 64 + m * 16 + l16;
        if (rrow > M - 1) rrow = M - 1;
        aoff[m] = (size_t)rrow * sa + lk * 8;
    }

    f32x4 acc[4][4] = {};

    auto step = [&](const bf16x8* af, const int kel) {
        bf16x8 bv[4];
        #pragma unroll
        for (int n = 0; n < 4; ++n) bv[n] = *(const bf16x8*)(bp[n] + kel);
        #pragma unroll
        for (int m = 0; m < 4; ++m)
            #pragma unroll
            for (int n = 0; n < 4; ++n)
                acc[m][n] = __builtin_amdgcn_mfma_f32_16x16x32_bf16(
                    bv[n], af[m], acc[m][n], 0, 0, 0);
    };

    if constexpr (AMODE == 0) {
        const ushort* Ab = (const ushort*)Av;
        #pragma unroll 4
        for (int kt = 0; kt < K / 32; ++kt) {
            bf16x8 af[4];
            #pragma unroll
            for (int m = 0; m < 4; ++m)
                af[m] = *(const bf16x8*)(Ab + aoff[m] + kt * 32);
            step(af, kt * 32);
        }
    } else {
        const float* Af = (const float*)Av;
        const float* Ag = (const float*)A2v;
        #pragma unroll 2
        for (int kt = 0; kt < 8; ++kt) {
            bf16x8 af[4];
            #pragma unroll
            for (int m = 0; m < 4; ++m) af[m] = ld_cvt(Af + aoff[m] + kt * 32);
            step(af, kt * 32);
        }
        #pragma unroll 2
        for (int kt = 0; kt < 8; ++kt) {
            bf16x8 af[4];
            #pragma unroll
            for (int m = 0; m < 4; ++m) af[m] = ld_cvt(Ag + aoff[m] + kt * 32);
            step(af, 256 + kt * 32);
        }
    }

    // epilogue: swapped-operand layout -> lane owns 4 consecutive cols per (m,n)
    #pragma unroll
    for (int m = 0; m < 4; ++m) {
        const int grow = row0 + wm * 64 + m * 16 + l16;
        if (grow >= M) continue;
        ushort* crow = C + (size_t)grow * N;
        #pragma unroll
        for (int n = 0; n < 4; ++n) {
            const int col4 = col0 + wn * 64 + n * 16 + lk * 4;
            float4 bs = *(const float4*)(bias + col4);
            f32x4 v = acc[m][n];
            float o0 = v[0] + bs.x, o1 = v[1] + bs.y, o2 = v[2] + bs.z, o3 = v[3] + bs.w;
            if (RELU) {
                o0 = fmaxf(o0, 0.f); o1 = fmaxf(o1, 0.f);
                o2 = fmaxf(o2, 0.f); o3 = fmaxf(o3, 0.f);
            }
            uint2 st = make_uint2(pkbf(o0, o1), pkbf(o2, o3));
            *(uint2*)(crow + col4) = st;
        }
    }
}

// ---------------- MS-deformable sampling: 1 block = 2 queries ----------------
// comb row layout: [value 256 | off 256 | attn 128] bf16, stride 640.
__global__ __launch_bounds__(256) void sample_kernel(
    const ushort* __restrict__ comb,
    const float* __restrict__ ref,     // (BL, 8)
    ushort* __restrict__ outbf)        // (BL, 256) bf16
{
    constexpr int Hs[4] = {100, 50, 25, 13};
    constexpr int Ws[4] = {152, 76, 38, 19};
    constexpr int St[4] = {0, 15200, 19000, 19950};
    constexpr int NWG = BL_C / 2;      // 20197

    const int orig = blockIdx.x;
    const int qd = NWG / 8, rr = NWG % 8;
    const int xcd = orig & 7, pos = orig >> 3;
    const int blk = (xcd < rr ? xcd * (qd + 1) : rr * (qd + 1) + (xcd - rr) * qd) + pos;
    const int bq0 = blk * 2;

    __shared__ __align__(16) float2 s_iw[2][8][64];

    const int t = threadIdx.x;
    const int qi = t >> 7, r2 = t & 127;
    const int bq = bq0 + qi;
    const int b = (bq >= LEN_IN_C) ? 1 : 0;
    const ushort* crow = comb + (size_t)bq * 640;

    // ---- phase 1: per (h, point): softmax weight + 4 corner (idx, w) ----
    {
        const int h = r2 >> 4, i = r2 & 15, l = i >> 2, p = i & 3;
        float lg = bf2f(crow[512 + h * 16 + i]);
        float mx = lg;
        #pragma unroll
        for (int o = 1; o < 16; o <<= 1) mx = fmaxf(mx, __shfl_xor(mx, o, 16));
        float e = __expf(lg - mx), sm = e;
        #pragma unroll
        for (int o = 1; o < 16; o <<= 1) sm += __shfl_xor(sm, o, 16);
        const float aw = e / sm;

        const uint ov = *(const uint*)(crow + 256 + h * 32 + l * 8 + p * 2);
        const float ox = __uint_as_float(ov << 16);
        const float oy = __uint_as_float(ov & 0xffff0000u);
        const float rx = ref[(size_t)bq * 8 + l * 2 + 0];
        const float ry = ref[(size_t)bq * 8 + l * 2 + 1];
        const int H = Hs[l], W = Ws[l];
        const float x = rx * (float)W + ox - 0.5f;
        const float y = ry * (float)H + oy - 0.5f;
        const float x0f = floorf(x), y0f = floorf(y);
        const float fx = x - x0f, fy = y - y0f;
        const int x0 = (int)x0f, y0 = (int)y0f;
        #pragma unroll
        for (int c = 0; c < 4; ++c) {
            const int dx = c & 1, dy = c >> 1;
            const int xi = x0 + dx, yi = y0 + dy;
            const bool valid = (xi >= 0) & (xi < W) & (yi >= 0) & (yi < H);
            float wgt = (dx ? fx : 1.f - fx) * (dy ? fy : 1.f - fy) * aw;
            if (!valid) wgt = 0.f;
            const int xc = xi < 0 ? 0 : (xi > W - 1 ? W - 1 : xi);
            const int yc = yi < 0 ? 0 : (yi > H - 1 ? H - 1 : yi);
            const int idx = St[l] + yc * W + xc;
            s_iw[qi][h][i * 4 + c] = make_float2(__int_as_float(idx), wgt);
        }
    }
    __syncthreads();

    // ---- phase 2: gather-FMA, 2 channels per thread ----
    const int h2 = r2 >> 4, d2 = r2 & 15;
    const uint* vbase = (const uint*)(comb + (size_t)b * LEN_IN_C * 640 + h2 * 32 + d2 * 2);
    float a0 = 0.f, a1 = 0.f;
    #pragma unroll 8
    for (int j = 0; j < 64; j += 2) {
        float4 iw = *(const float4*)&s_iw[qi][h2][j];
        const int  i0 = __float_as_int(iw.x); const float w0 = iw.y;
        const int  i1 = __float_as_int(iw.z); const float w1 = iw.w;
        const uint v0 = vbase[(size_t)i0 * 320];
        const uint v1 = vbase[(size_t)i1 * 320];
        a0 += w0 * __uint_as_float(v0 << 16);
        a1 += w0 * __uint_as_float(v0 & 0xffff0000u);
        a0 += w1 * __uint_as_float(v1 << 16);
        a1 += w1 * __uint_as_float(v1 & 0xffff0000u);
    }
    const uint o = ((uint)f2bf(a1) << 16) | (uint)f2bf(a0);
    *(uint*)(outbf + (size_t)bq * 256 + h2 * 32 + d2 * 2) = o;
}

// ---------------- fused residual-add + LayerNorm: wave per row ----------------
template <bool ABF, bool OF32>
__global__ __launch_bounds__(256) void add_ln(
    const void* __restrict__ ap, const ushort* __restrict__ bp,
    const float* __restrict__ g, const float* __restrict__ be,
    void* __restrict__ op)
{
    const int row = blockIdx.x * 4 + (threadIdx.x >> 6);
    if (row >= BL_C) return;
    const int ln = threadIdx.x & 63;
    const size_t base = (size_t)row * 256 + ln * 4;

    float x[4];
    if (ABF) {
        ushort4 a4 = *(const ushort4*)((const ushort*)ap + base);
        x[0] = bf2f(a4.x); x[1] = bf2f(a4.y); x[2] = bf2f(a4.z); x[3] = bf2f(a4.w);
    } else {
        float4 a4 = *(const float4*)((const float*)ap + base);
        x[0] = a4.x; x[1] = a4.y; x[2] = a4.z; x[3] = a4.w;
    }
    ushort4 b4 = *(const ushort4*)(bp + base);
    x[0] += bf2f(b4.x); x[1] += bf2f(b4.y); x[2] += bf2f(b4.z); x[3] += bf2f(b4.w);

    float s = x[0] + x[1] + x[2] + x[3];
    #pragma unroll
    for (int o = 32; o >= 1; o >>= 1) s += __shfl_xor(s, o, 64);
    const float mean = s * (1.f / 256.f);
    float d0 = x[0] - mean, d1 = x[1] - mean, d2 = x[2] - mean, d3 = x[3] - mean;
    float ss = d0 * d0 + d1 * d1 + d2 * d2 + d3 * d3;
    #pragma unroll
    for (int o = 32; o >= 1; o >>= 1) ss += __shfl_xor(ss, o, 64);
    const float rs = rsqrtf(ss * (1.f / 256.f) + 1e-5f);

    float4 gv = *(const float4*)(g + ln * 4);
    float4 bv = *(const float4*)(be + ln * 4);
    float o0 = d0 * rs * gv.x + bv.x;
    float o1 = d1 * rs * gv.y + bv.y;
    float o2 = d2 * rs * gv.z + bv.z;
    float o3 = d3 * rs * gv.w + bv.w;

    if (OF32) {
        *(float4*)((float*)op + base) = make_float4(o0, o1, o2, o3);
    } else {
        ushort4 st;
        st.x = f2bf(o0); st.y = f2bf(o1); st.z = f2bf(o2); st.w = f2bf(o3);
        *(ushort4*)((ushort*)op + base) = st;
    }
}

extern "C" void kernel_launch(void* const* d_in, const int* in_sizes, int n_in,
                              void* d_out, int out_size, void* d_ws, size_t ws_size,
                              hipStream_t stream) {
    const float* src    = (const float*)d_in[0];
    const float* pos    = (const float*)d_in[1];
    const float* refpts = (const float*)d_in[2];
    const float* W_off  = (const float*)d_in[5];
    const float* b_off  = (const float*)d_in[6];
    const float* W_attn = (const float*)d_in[7];
    const float* b_attn = (const float*)d_in[8];
    const float* W_val  = (const float*)d_in[9];
    const float* b_val  = (const float*)d_in[10];
    const float* W_out  = (const float*)d_in[11];
    const float* b_out  = (const float*)d_in[12];
    const float* W1     = (const float*)d_in[13];
    const float* b1     = (const float*)d_in[14];
    const float* W2     = (const float*)d_in[15];
    const float* b2     = (const float*)d_in[16];
    const float* g1     = (const float*)d_in[17];
    const float* be1    = (const float*)d_in[18];
    const float* g2     = (const float*)d_in[19];
    const float* be2    = (const float*)d_in[20];
    float* out = (float*)d_out;
    (void)in_sizes; (void)n_in; (void)out_size; (void)ws_size;

    const int BL = BL_C;
    char* ws = (char*)d_ws;
    // layout (bytes)
    const size_t COMB_B = (size_t)BL * 640 * 2;     // 51,704,320
    const size_t HALF_B = (size_t)BL * 256 * 2;     // 20,681,728
    ushort* comb_bf = (ushort*)(ws);                         // [0, COMB)
    ushort* ao_bf   = (ushort*)(ws + COMB_B);                // attn-sample out
    ushort* src2_bf = (ushort*)(ws + COMB_B + HALF_B);
    ushort* mid_bf  = (ushort*)(ws);                         // overlays comb+ao (dead)
    ushort* x_bf    = (ushort*)(ws + COMB_B + 2 * HALF_B);
    ushort* ffn2_bf = (ushort*)(ws + COMB_B + 3 * HALF_B);
    char*   wts     = ws + COMB_B + 4 * HALF_B;
    ushort* Tcomb = (ushort*)(wts);                          // 640*512
    ushort* Tout  = Tcomb + 640 * 512;                       // 256*256
    ushort* TW1   = Tout + 256 * 256;                        // 1024*256
    ushort* TW2   = TW1 + 1024 * 256;                        // 256*1024
    float*  bcomb = (float*)(TW2 + 256 * 1024);              // 640

    dim3 blk(256);
    const int Mt = (BL + 127) / 128;   // 316

    // weight prep
    build_comb<<<dim3(640 * 128 / 256), blk, 0, stream>>>(W_val, W_off, W_attn, Tcomb);
    build_bias<<<dim3(3), blk, 0, stream>>>(b_val, b_off, b_attn, bcomb);
    transpose_cast<<<dim3(8, 8), blk, 0, stream>>>(W_out, Tout, 256, 256);
    transpose_cast<<<dim3(32, 8), blk, 0, stream>>>(W1, TW1, 256, 1024);
    transpose_cast<<<dim3(8, 32), blk, 0, stream>>>(W2, TW2, 1024, 256);

    // [value|off|attn] = [src|pos] @ Tcomb^T + bcomb   (M=BL, N=640, K=512)
    gemm_dr<3, false><<<dim3(Mt * 5), blk, 0, stream>>>(
        src, pos, Tcomb, bcomb, comb_bf, BL, 640, 512, 256, 5, Mt * 5);

    // deformable sampling -> ao_bf
    sample_kernel<<<dim3(BL / 2), blk, 0, stream>>>(comb_bf, refpts, ao_bf);

    // src2 = ao @ W_out + b_out
    gemm_dr<0, false><<<dim3(Mt * 2), blk, 0, stream>>>(
        ao_bf, nullptr, Tout, b_out, src2_bf, BL, 256, 256, 256, 2, Mt * 2);

    // x = LN(src + src2) -> bf16
    add_ln<false, false><<<dim3((BL + 3) / 4), blk, 0, stream>>>(src, src2_bf, g1, be1, x_bf);

    // mid = relu(x @ W1 + b1)
    gemm_dr<0, true><<<dim3(Mt * 8), blk, 0, stream>>>(
        x_bf, nullptr, TW1, b1, mid_bf, BL, 1024, 256, 256, 8, Mt * 8);

    // ffn2 = mid @ W2 + b2
    gemm_dr<0, false><<<dim3(Mt * 2), blk, 0, stream>>>(
        mid_bf, nullptr, TW2, b2, ffn2_bf, BL, 256, 1024, 1024, 2, Mt * 2);

    // out = LN(x + ffn2) -> f32
    add_ln<true, true><<<dim3((BL + 3) / 4), blk, 0, stream>>>(x_bf, ffn2_bf, g2, be2, out);
}